// Round 12
// baseline (1152.519 us; speedup 1.0000x reference)
//
#include <hip/hip_runtime.h>

#define NCP    64
#define BTS    16
#define NTPL   2048
#define TSTEPS 6
#define DTF    0.2f                      // 1/(T-1)
#define L2E    1.4426950408889634f       // log2(e)

// ---------- fast scalar helpers ----------
__device__ __forceinline__ float fast_rcp(float x) { return __builtin_amdgcn_rcpf(x); }
__device__ __forceinline__ float fexp2(float x)    { return __builtin_amdgcn_exp2f(x); }
__device__ __forceinline__ float fast_tanh(float x) {        // shoot path
    float e = __expf(2.0f * x);
    return 1.0f - 2.0f * fast_rcp(1.0f + e);
}

// 4 sigmoids r_i = 1/(1+exp2(t_i)) with ONE v_rcp (product-of-denominators).
// |t| <= ~25 here -> d <= 4e8, 4-product <= ~1e35 < FLT_MAX: safe.
__device__ __forceinline__ void sig4(float t0, float t1, float t2, float t3,
                                     float& r0, float& r1, float& r2, float& r3)
{
    float d0 = 1.0f + fexp2(t0);
    float d1 = 1.0f + fexp2(t1);
    float d2 = 1.0f + fexp2(t2);
    float d3 = 1.0f + fexp2(t3);
    float p01 = d0 * d1, p23 = d2 * d3;
    float inv = fast_rcp(p01 * p23);
    float i01 = inv * p23, i23 = inv * p01;
    r0 = d1 * i01;  r1 = d0 * i01;
    r2 = d3 * i23;  r3 = d2 * i23;
}

// ======================================================================
// Symmetrized 2x2 kernel block, transformed sigmoid weights, hot weights
// VGPR/shfl-resident (R11-proven: kills s_load churn; DS pipe overlaps
// VALU). Sigmoid rcp shared 4-ways (trans 84 -> 54 per pair).
// Local w layout: [0..39]=W1t [40..49]=b1t [50..149]=W2t
//                 [150..159]=C0 [160..169]=C1 [170..179]=C2
// Global wt layout: W1t[0..39] b1t[40..49] W2t[50..149] b2t[150..159]
//                   C0[160..169] C1[170..179] C2[180..189] b3t[190..192]
// ======================================================================
__device__ __forceinline__ void kblock(
    float x0, float x1, float p0, float p1,
    const float (&w)[180], const float* __restrict__ wt,
    float& M00, float& M01, float& M11)
{
    float ra[10], rb[10];
#pragma unroll
    for (int k = 0; k < 10; k += 2) {
        float ta0 = fmaf(p1, w[30 + k],
                    fmaf(p0, w[20 + k],
                    fmaf(x1, w[10 + k],
                    fmaf(x0, w[k], w[40 + k]))));
        float tb0 = fmaf(x1, w[30 + k],
                    fmaf(x0, w[20 + k],
                    fmaf(p1, w[10 + k],
                    fmaf(p0, w[k], w[40 + k]))));
        float ta1 = fmaf(p1, w[31 + k],
                    fmaf(p0, w[21 + k],
                    fmaf(x1, w[11 + k],
                    fmaf(x0, w[k + 1], w[41 + k]))));
        float tb1 = fmaf(x1, w[31 + k],
                    fmaf(x0, w[21 + k],
                    fmaf(p1, w[11 + k],
                    fmaf(p0, w[k + 1], w[41 + k]))));
        sig4(ta0, tb0, ta1, tb1, ra[k], rb[k], ra[k + 1], rb[k + 1]);
    }
    float ua[10], ub[10];
#pragma unroll
    for (int k = 0; k < 10; ++k) {
        float bb = wt[150 + k];          // b2t: cold, once per kblock
        ua[k] = fmaf(ra[0], w[50 + k], bb);
        ub[k] = fmaf(rb[0], w[50 + k], bb);
    }
#pragma unroll
    for (int c = 1; c < 10; ++c) {
#pragma unroll
        for (int k = 0; k < 10; ++k) {
            float ww = w[50 + c * 10 + k];
            ua[k] = fmaf(ra[c], ww, ua[k]);
            ub[k] = fmaf(rb[c], ww, ub[k]);
        }
    }
    float Oa = wt[190], Ob = wt[190];
    float T1a = wt[191], T1b = wt[191];
    float T2a = wt[192], T2b = wt[192];
#pragma unroll
    for (int c = 0; c < 10; c += 2) {
        float g0a, g0b, g1a, g1b;
        sig4(ua[c], ub[c], ua[c + 1], ub[c + 1], g0a, g0b, g1a, g1b);
        Oa  = fmaf(g0a, w[150 + c], Oa);   Ob  = fmaf(g0b, w[150 + c], Ob);
        T1a = fmaf(g0a, w[160 + c], T1a);  T1b = fmaf(g0b, w[160 + c], T1b);
        T2a = fmaf(g0a, w[170 + c], T2a);  T2b = fmaf(g0b, w[170 + c], T2b);
        Oa  = fmaf(g1a, w[151 + c], Oa);   Ob  = fmaf(g1b, w[151 + c], Ob);
        T1a = fmaf(g1a, w[161 + c], T1a);  T1b = fmaf(g1b, w[161 + c], T1b);
        T2a = fmaf(g1a, w[171 + c], T2a);  T2b = fmaf(g1b, w[171 + c], T2b);
    }
    M00 = fexp2(T1a) + fexp2(T1b);   // 0.5*(exp(o1a)+exp(o1b))
    M01 = Oa + Ob;
    M11 = fexp2(T2a) + fexp2(T2b);
}

// Load the 180 hot weights: 3 lane-strided vector loads + __shfl distribute.
__device__ __forceinline__ void load_w(const float* __restrict__ wt,
                                       int lane, float (&w)[180])
{
    float c0 = wt[lane];            // wt[0..63]
    float c1 = wt[64 + lane];       // wt[64..127]
    float c2 = wt[128 + lane];      // wt[128..191]
#pragma unroll
    for (int t = 0; t < 180; ++t) {
        int src = (t < 150) ? t : (t + 10);   // skip b2t at wt[150..159]
        int ch = src >> 6, ix = src & 63;
        float v = (ch == 0) ? c0 : (ch == 1) ? c1 : c2;
        w[t] = __shfl(v, ix);
    }
}

// ======================================================================
// One symplectic shooting step (R2/R6/R9-proven). Grid 1024(+1 on first).
// first!=0: read p from cp / q from q0; block 1024 folds wt instead.
// ======================================================================
__global__ __launch_bounds__(64, 1)
void shoot_step(const float* __restrict__ q0, const float* __restrict__ cp,
                const float* __restrict__ p_in, const float* __restrict__ q_in,
                float* __restrict__ p_out, float* __restrict__ q_out,
                const float* __restrict__ W1, const float* __restrict__ b1,
                const float* __restrict__ W2, const float* __restrict__ b2,
                const float* __restrict__ W3, const float* __restrict__ b3,
                float* __restrict__ wt, int first)
{
    int blk = blockIdx.x;
    if (first && blk == BTS * NCP) {
        int t = threadIdx.x;
        if (t < 40) wt[t] = 2.0f * L2E * W1[t];
        if (t < 10) wt[40 + t] = 2.0f * L2E * b1[t];
        for (int i = t; i < 100; i += 64) wt[50 + i] = -4.0f * L2E * W2[i];
        if (t < 10) {
            float s = b2[t];
            for (int c = 0; c < 10; ++c) s += W2[c * 10 + t];
            wt[150 + t] = 2.0f * L2E * s;                 // b2''
            wt[160 + t] = -W3[t * 3 + 0];                 // C0 (0.5 * -2)
            wt[170 + t] = -2.0f * L2E * W3[t * 3 + 1];    // C1
            wt[180 + t] = -2.0f * L2E * W3[t * 3 + 2];    // C2
        }
        if (t < 3) {
            float s = b3[t];
            for (int c = 0; c < 10; ++c) s += W3[c * 3 + t];
            wt[190 + t] = (t == 0) ? 0.5f * s : fmaf(L2E, s, -1.0f);
        }
        return;
    }

    int batch = blk >> 6;
    int a = blk & (NCP - 1);
    int b = threadIdx.x;

    float pax, pay, qax, qay, pbx, pby, qbx, qby;
    if (first) {
        pax = cp[2 * a]; pay = cp[2 * a + 1];
        pbx = cp[2 * b]; pby = cp[2 * b + 1];
        qax = q0[(batch * NCP + a) * 2 + 0]; qay = q0[(batch * NCP + a) * 2 + 1];
        qbx = q0[(batch * NCP + b) * 2 + 0]; qby = q0[(batch * NCP + b) * 2 + 1];
    } else {
        const float* pB = p_in + batch * NCP * 2;
        const float* qB = q_in + batch * NCP * 2;
        pax = pB[a * 2 + 0]; pay = pB[a * 2 + 1];
        qax = qB[a * 2 + 0]; qay = qB[a * 2 + 1];
        pbx = pB[b * 2 + 0]; pby = pB[b * 2 + 1];
        qbx = qB[b * 2 + 0]; qby = qB[b * 2 + 1];
    }

    float dhq_x = 0.f, dhq_y = 0.f;
    float g_x = 0.f, g_y = 0.f;
    float cross = fmaf(qax, qby, qay * qbx);

#pragma unroll
    for (int e = 0; e < 2; ++e) {
        float z0 = e ? pbx : pax;
        float z1 = e ? pby : pay;
        float z2 = e ? pax : pbx;
        float z3 = e ? pay : pby;

        float h1[10];
#pragma unroll
        for (int k = 0; k < 10; ++k) {
            float u = fmaf(z3, W1[30 + k],
                      fmaf(z2, W1[20 + k],
                      fmaf(z1, W1[10 + k],
                      fmaf(z0, W1[k], b1[k]))));
            h1[k] = fast_tanh(u);
        }
        float u2[10];
#pragma unroll
        for (int k = 0; k < 10; ++k) u2[k] = b2[k];
#pragma unroll
        for (int c = 0; c < 10; ++c) {
#pragma unroll
            for (int k = 0; k < 10; ++k) u2[k] = fmaf(h1[c], W2[c * 10 + k], u2[k]);
        }
        float h2[10];
        float o0 = b3[0], o1 = b3[1], o2 = b3[2];
#pragma unroll
        for (int c = 0; c < 10; ++c) {
            h2[c] = fast_tanh(u2[c]);
            o0 = fmaf(h2[c], W3[c * 3 + 0], o0);
            o1 = fmaf(h2[c], W3[c * 3 + 1], o1);
            o2 = fmaf(h2[c], W3[c * 3 + 2], o2);
        }
        float e1 = __expf(o1), e2 = __expf(o2);

        dhq_x = fmaf(0.5f, fmaf(e1, qbx, o0 * qby), dhq_x);
        dhq_y = fmaf(0.5f, fmaf(o0, qbx, e2 * qby), dhq_y);

        float d0 = cross;
        float d1 = e1 * qax * qbx;
        float d2 = e2 * qay * qby;

        float du2[10];
#pragma unroll
        for (int c = 0; c < 10; ++c) {
            float dh2 = fmaf(W3[c * 3 + 0], d0,
                        fmaf(W3[c * 3 + 1], d1, W3[c * 3 + 2] * d2));
            du2[c] = dh2 * (1.0f - h2[c] * h2[c]);
        }
        float du1[10];
#pragma unroll
        for (int c = 0; c < 10; ++c) {
            float dh1 = 0.f;
#pragma unroll
            for (int k = 0; k < 10; ++k) dh1 = fmaf(W2[c * 10 + k], du2[k], dh1);
            du1[c] = dh1 * (1.0f - h1[c] * h1[c]);
        }
        int c0 = e ? 2 : 0;
        float ga = 0.f, gb = 0.f;
#pragma unroll
        for (int k = 0; k < 10; ++k) {
            ga = fmaf(W1[(0 + c0) * 10 + k], du1[k], ga);
            gb = fmaf(W1[(1 + c0) * 10 + k], du1[k], gb);
        }
        g_x = fmaf(0.5f, ga, g_x);
        g_y = fmaf(0.5f, gb, g_y);
    }

#pragma unroll
    for (int off = 32; off > 0; off >>= 1) {
        dhq_x += __shfl_xor(dhq_x, off);
        dhq_y += __shfl_xor(dhq_y, off);
        g_x   += __shfl_xor(g_x, off);
        g_y   += __shfl_xor(g_y, off);
    }

    if (b == 0) {
        float* pO = p_out + (batch * NCP + a) * 2;
        float* qO = q_out + (batch * NCP + a) * 2;
        pO[0] = fmaf(DTF, dhq_x, pax);
        pO[1] = fmaf(DTF, dhq_y, pay);
        qO[0] = fmaf(-DTF, g_x, qax);
        qO[1] = fmaf(-DTF, g_y, qay);
    }
}

// ======================================================================
// Flow step 0: x == tpl, p == cp for ALL batches -> one kblock per (i,j),
// apply all 16 batches' q. Writes x^(1) into d_out. One wave per block.
// ======================================================================
__global__ __launch_bounds__(64, 4)
void flow_step0(const float* __restrict__ tpl, const float* __restrict__ cp,
                const float* __restrict__ q0, float* __restrict__ out,
                const float* __restrict__ wt)
{
    int i = blockIdx.x;
    int j = threadIdx.x;

    float w[180];
    load_w(wt, j, w);

    float x0 = tpl[2 * i], x1 = tpl[2 * i + 1];
    float p0 = cp[2 * j],  p1 = cp[2 * j + 1];

    float M00, M01, M11;
    kblock(x0, x1, p0, p1, w, wt, M00, M01, M11);

    const float2* __restrict__ q = (const float2*)q0;
#pragma unroll
    for (int bt = 0; bt < BTS; ++bt) {
        float2 qq = q[bt * NCP + j];
        float vx = fmaf(M00, qq.x, M01 * qq.y);
        float vy = fmaf(M01, qq.x, M11 * qq.y);
#pragma unroll
        for (int off = 32; off > 0; off >>= 1) {
            vx += __shfl_xor(vx, off);
            vy += __shfl_xor(vy, off);
        }
        if (j == 0) {
            out[((size_t)bt * NTPL + i) * 2 + 0] = fmaf(DTF, vx, x0);
            out[((size_t)bt * NTPL + i) * 2 + 1] = fmaf(DTF, vy, x1);
        }
    }
}

// ======================================================================
// Flow steps 1..6: one wave per (batch, i); lane = control point j.
// ======================================================================
__global__ __launch_bounds__(64, 4)
void flow_rest(const float* __restrict__ p_hist, const float* __restrict__ q_hist,
               float* __restrict__ out, const float* __restrict__ wt)
{
    int unit = blockIdx.x;
    int j = threadIdx.x;
    int batch = unit >> 11;
    int i = unit & (NTPL - 1);

    float w[180];
    load_w(wt, j, w);

    const float2* __restrict__ ph = (const float2*)p_hist;
    const float2* __restrict__ qh = (const float2*)q_hist;

    size_t oidx = ((size_t)batch * NTPL + i) * 2;
    float x0 = out[oidx + 0];
    float x1 = out[oidx + 1];

#pragma unroll
    for (int s = 0; s < TSTEPS; ++s) {
        int idx = ((s + 1) * BTS + batch) * NCP + j;
        float2 P = ph[idx];
        float2 Q = qh[idx];
        float M00, M01, M11;
        kblock(x0, x1, P.x, P.y, w, wt, M00, M01, M11);
        float vx = fmaf(M00, Q.x, M01 * Q.y);
        float vy = fmaf(M01, Q.x, M11 * Q.y);
#pragma unroll
        for (int off = 32; off > 0; off >>= 1) {
            vx += __shfl_xor(vx, off);
            vy += __shfl_xor(vy, off);
        }
        x0 = fmaf(DTF, vx, x0);
        x1 = fmaf(DTF, vy, x1);
    }

    if (j == 0) {
        out[oidx + 0] = x0;
        out[oidx + 1] = x1;
    }
}

extern "C" void kernel_launch(void* const* d_in, const int* in_sizes, int n_in,
                              void* d_out, int out_size, void* d_ws, size_t ws_size,
                              hipStream_t stream)
{
    const float* q0  = (const float*)d_in[0];   // [16,64,2]
    const float* tpl = (const float*)d_in[1];   // [2048,2]
    const float* cp  = (const float*)d_in[2];   // [64,2]
    const float* W1  = (const float*)d_in[3];   // [4,10]
    const float* b1  = (const float*)d_in[4];   // [10]
    const float* W2  = (const float*)d_in[5];   // [10,10]
    const float* b2  = (const float*)d_in[6];   // [10]
    const float* W3  = (const float*)d_in[7];   // [10,3]
    const float* b3  = (const float*)d_in[8];   // [3]
    float* out = (float*)d_out;

    float* ws = (float*)d_ws;
    const int slab = BTS * NCP * 2;                      // 2048 floats / slice
    float* p_hist = ws;                                  // 7 slabs (slot 0 unused)
    float* q_hist = ws + (size_t)7 * slab;
    float* wt     = ws + (size_t)14 * slab;              // 193 floats

    shoot_step<<<BTS * NCP + 1, 64, 0, stream>>>(
        q0, cp, nullptr, nullptr,
        p_hist + (size_t)1 * slab, q_hist + (size_t)1 * slab,
        W1, b1, W2, b2, W3, b3, wt, 1);
    for (int s = 1; s < TSTEPS; ++s) {
        shoot_step<<<BTS * NCP, 64, 0, stream>>>(
            q0, cp,
            p_hist + (size_t)s * slab, q_hist + (size_t)s * slab,
            p_hist + (size_t)(s + 1) * slab, q_hist + (size_t)(s + 1) * slab,
            W1, b1, W2, b2, W3, b3, wt, 0);
    }

    flow_step0<<<NTPL, 64, 0, stream>>>(tpl, cp, q0, out, wt);
    flow_rest<<<BTS * NTPL, 64, 0, stream>>>(p_hist, q_hist, out, wt);
}

// Round 13
// 348.026 us; speedup vs baseline: 3.3116x; 3.3116x over previous
//
#include <hip/hip_runtime.h>

#define NCP    64
#define BTS    16
#define NTPL   2048
#define TSTEPS 6
#define DTF    0.2f                      // 1/(T-1)
#define L2E    1.4426950408889634f       // log2(e)

// ---------- fast scalar helpers ----------
__device__ __forceinline__ float fast_rcp(float x) { return __builtin_amdgcn_rcpf(x); }
__device__ __forceinline__ float fexp2(float x)    { return __builtin_amdgcn_exp2f(x); }
__device__ __forceinline__ float fast_tanh(float x) {        // shoot path
    float e = __expf(2.0f * x);
    return 1.0f - 2.0f * fast_rcp(1.0f + e);
}

// 4 sigmoids r_i = 1/(1+exp2(t_i)) with ONE v_rcp (product-of-denominators).
// |t| <= ~25 here -> d <= 4e8, 4-product <= ~1e35 < FLT_MAX: safe.
__device__ __forceinline__ void sig4(float t0, float t1, float t2, float t3,
                                     float& r0, float& r1, float& r2, float& r3)
{
    float d0 = 1.0f + fexp2(t0);
    float d1 = 1.0f + fexp2(t1);
    float d2 = 1.0f + fexp2(t2);
    float d3 = 1.0f + fexp2(t3);
    float p01 = d0 * d1, p23 = d2 * d3;
    float inv = fast_rcp(p01 * p23);
    float i01 = inv * p23, i23 = inv * p01;
    r0 = d1 * i01;  r1 = d0 * i01;
    r2 = d3 * i23;  r3 = d2 * i23;
}

// ======================================================================
// Symmetrized 2x2 kernel block, transformed sigmoid weights, hot weights
// VGPR/shfl-resident (R11-proven). sig4: trans 84 -> 54 per pair.
// REQUIRES a >=256-VGPR budget (launch_bounds(256,1)); at 128 the w[180]
// array spills to scratch catastrophically (R12: 4 GB HBM traffic).
// Local w layout: [0..39]=W1t [40..49]=b1t [50..149]=W2t
//                 [150..159]=C0 [160..169]=C1 [170..179]=C2
// Global wt layout: W1t[0..39] b1t[40..49] W2t[50..149] b2t[150..159]
//                   C0[160..169] C1[170..179] C2[180..189] b3t[190..192]
// ======================================================================
__device__ __forceinline__ void kblock(
    float x0, float x1, float p0, float p1,
    const float (&w)[180], const float* __restrict__ wt,
    float& M00, float& M01, float& M11)
{
    float ra[10], rb[10];
#pragma unroll
    for (int k = 0; k < 10; k += 2) {
        float ta0 = fmaf(p1, w[30 + k],
                    fmaf(p0, w[20 + k],
                    fmaf(x1, w[10 + k],
                    fmaf(x0, w[k], w[40 + k]))));
        float tb0 = fmaf(x1, w[30 + k],
                    fmaf(x0, w[20 + k],
                    fmaf(p1, w[10 + k],
                    fmaf(p0, w[k], w[40 + k]))));
        float ta1 = fmaf(p1, w[31 + k],
                    fmaf(p0, w[21 + k],
                    fmaf(x1, w[11 + k],
                    fmaf(x0, w[k + 1], w[41 + k]))));
        float tb1 = fmaf(x1, w[31 + k],
                    fmaf(x0, w[21 + k],
                    fmaf(p1, w[11 + k],
                    fmaf(p0, w[k + 1], w[41 + k]))));
        sig4(ta0, tb0, ta1, tb1, ra[k], rb[k], ra[k + 1], rb[k + 1]);
    }
    float ua[10], ub[10];
#pragma unroll
    for (int k = 0; k < 10; ++k) {
        float bb = wt[150 + k];          // b2t: cold, once per kblock
        ua[k] = fmaf(ra[0], w[50 + k], bb);
        ub[k] = fmaf(rb[0], w[50 + k], bb);
    }
#pragma unroll
    for (int c = 1; c < 10; ++c) {
#pragma unroll
        for (int k = 0; k < 10; ++k) {
            float ww = w[50 + c * 10 + k];
            ua[k] = fmaf(ra[c], ww, ua[k]);
            ub[k] = fmaf(rb[c], ww, ub[k]);
        }
    }
    float Oa = wt[190], Ob = wt[190];
    float T1a = wt[191], T1b = wt[191];
    float T2a = wt[192], T2b = wt[192];
#pragma unroll
    for (int c = 0; c < 10; c += 2) {
        float g0a, g0b, g1a, g1b;
        sig4(ua[c], ub[c], ua[c + 1], ub[c + 1], g0a, g0b, g1a, g1b);
        Oa  = fmaf(g0a, w[150 + c], Oa);   Ob  = fmaf(g0b, w[150 + c], Ob);
        T1a = fmaf(g0a, w[160 + c], T1a);  T1b = fmaf(g0b, w[160 + c], T1b);
        T2a = fmaf(g0a, w[170 + c], T2a);  T2b = fmaf(g0b, w[170 + c], T2b);
        Oa  = fmaf(g1a, w[151 + c], Oa);   Ob  = fmaf(g1b, w[151 + c], Ob);
        T1a = fmaf(g1a, w[161 + c], T1a);  T1b = fmaf(g1b, w[161 + c], T1b);
        T2a = fmaf(g1a, w[171 + c], T2a);  T2b = fmaf(g1b, w[171 + c], T2b);
    }
    M00 = fexp2(T1a) + fexp2(T1b);   // 0.5*(exp(o1a)+exp(o1b))
    M01 = Oa + Ob;
    M11 = fexp2(T2a) + fexp2(T2b);
}

// Load the 180 hot weights: 3 lane-strided vector loads + __shfl distribute.
__device__ __forceinline__ void load_w(const float* __restrict__ wt,
                                       int lane, float (&w)[180])
{
    float c0 = wt[lane];            // wt[0..63]
    float c1 = wt[64 + lane];       // wt[64..127]
    float c2 = wt[128 + lane];      // wt[128..191]
#pragma unroll
    for (int t = 0; t < 180; ++t) {
        int src = (t < 150) ? t : (t + 10);   // skip b2t at wt[150..159]
        int ch = src >> 6, ix = src & 63;
        float v = (ch == 0) ? c0 : (ch == 1) ? c1 : c2;
        w[t] = __shfl(v, ix);
    }
}

// ======================================================================
// One symplectic shooting step (R2/R6/R9-proven). Grid 1024(+1 on first).
// first!=0: read p from cp / q from q0; block 1024 folds wt instead.
// ======================================================================
__global__ __launch_bounds__(64, 1)
void shoot_step(const float* __restrict__ q0, const float* __restrict__ cp,
                const float* __restrict__ p_in, const float* __restrict__ q_in,
                float* __restrict__ p_out, float* __restrict__ q_out,
                const float* __restrict__ W1, const float* __restrict__ b1,
                const float* __restrict__ W2, const float* __restrict__ b2,
                const float* __restrict__ W3, const float* __restrict__ b3,
                float* __restrict__ wt, int first)
{
    int blk = blockIdx.x;
    if (first && blk == BTS * NCP) {
        int t = threadIdx.x;
        if (t < 40) wt[t] = 2.0f * L2E * W1[t];
        if (t < 10) wt[40 + t] = 2.0f * L2E * b1[t];
        for (int i = t; i < 100; i += 64) wt[50 + i] = -4.0f * L2E * W2[i];
        if (t < 10) {
            float s = b2[t];
            for (int c = 0; c < 10; ++c) s += W2[c * 10 + t];
            wt[150 + t] = 2.0f * L2E * s;                 // b2''
            wt[160 + t] = -W3[t * 3 + 0];                 // C0 (0.5 * -2)
            wt[170 + t] = -2.0f * L2E * W3[t * 3 + 1];    // C1
            wt[180 + t] = -2.0f * L2E * W3[t * 3 + 2];    // C2
        }
        if (t < 3) {
            float s = b3[t];
            for (int c = 0; c < 10; ++c) s += W3[c * 3 + t];
            wt[190 + t] = (t == 0) ? 0.5f * s : fmaf(L2E, s, -1.0f);
        }
        return;
    }

    int batch = blk >> 6;
    int a = blk & (NCP - 1);
    int b = threadIdx.x;

    float pax, pay, qax, qay, pbx, pby, qbx, qby;
    if (first) {
        pax = cp[2 * a]; pay = cp[2 * a + 1];
        pbx = cp[2 * b]; pby = cp[2 * b + 1];
        qax = q0[(batch * NCP + a) * 2 + 0]; qay = q0[(batch * NCP + a) * 2 + 1];
        qbx = q0[(batch * NCP + b) * 2 + 0]; qby = q0[(batch * NCP + b) * 2 + 1];
    } else {
        const float* pB = p_in + batch * NCP * 2;
        const float* qB = q_in + batch * NCP * 2;
        pax = pB[a * 2 + 0]; pay = pB[a * 2 + 1];
        qax = qB[a * 2 + 0]; qay = qB[a * 2 + 1];
        pbx = pB[b * 2 + 0]; pby = pB[b * 2 + 1];
        qbx = qB[b * 2 + 0]; qby = qB[b * 2 + 1];
    }

    float dhq_x = 0.f, dhq_y = 0.f;
    float g_x = 0.f, g_y = 0.f;
    float cross = fmaf(qax, qby, qay * qbx);

#pragma unroll
    for (int e = 0; e < 2; ++e) {
        float z0 = e ? pbx : pax;
        float z1 = e ? pby : pay;
        float z2 = e ? pax : pbx;
        float z3 = e ? pay : pby;

        float h1[10];
#pragma unroll
        for (int k = 0; k < 10; ++k) {
            float u = fmaf(z3, W1[30 + k],
                      fmaf(z2, W1[20 + k],
                      fmaf(z1, W1[10 + k],
                      fmaf(z0, W1[k], b1[k]))));
            h1[k] = fast_tanh(u);
        }
        float u2[10];
#pragma unroll
        for (int k = 0; k < 10; ++k) u2[k] = b2[k];
#pragma unroll
        for (int c = 0; c < 10; ++c) {
#pragma unroll
            for (int k = 0; k < 10; ++k) u2[k] = fmaf(h1[c], W2[c * 10 + k], u2[k]);
        }
        float h2[10];
        float o0 = b3[0], o1 = b3[1], o2 = b3[2];
#pragma unroll
        for (int c = 0; c < 10; ++c) {
            h2[c] = fast_tanh(u2[c]);
            o0 = fmaf(h2[c], W3[c * 3 + 0], o0);
            o1 = fmaf(h2[c], W3[c * 3 + 1], o1);
            o2 = fmaf(h2[c], W3[c * 3 + 2], o2);
        }
        float e1 = __expf(o1), e2 = __expf(o2);

        dhq_x = fmaf(0.5f, fmaf(e1, qbx, o0 * qby), dhq_x);
        dhq_y = fmaf(0.5f, fmaf(o0, qbx, e2 * qby), dhq_y);

        float d0 = cross;
        float d1 = e1 * qax * qbx;
        float d2 = e2 * qay * qby;

        float du2[10];
#pragma unroll
        for (int c = 0; c < 10; ++c) {
            float dh2 = fmaf(W3[c * 3 + 0], d0,
                        fmaf(W3[c * 3 + 1], d1, W3[c * 3 + 2] * d2));
            du2[c] = dh2 * (1.0f - h2[c] * h2[c]);
        }
        float du1[10];
#pragma unroll
        for (int c = 0; c < 10; ++c) {
            float dh1 = 0.f;
#pragma unroll
            for (int k = 0; k < 10; ++k) dh1 = fmaf(W2[c * 10 + k], du2[k], dh1);
            du1[c] = dh1 * (1.0f - h1[c] * h1[c]);
        }
        int c0 = e ? 2 : 0;
        float ga = 0.f, gb = 0.f;
#pragma unroll
        for (int k = 0; k < 10; ++k) {
            ga = fmaf(W1[(0 + c0) * 10 + k], du1[k], ga);
            gb = fmaf(W1[(1 + c0) * 10 + k], du1[k], gb);
        }
        g_x = fmaf(0.5f, ga, g_x);
        g_y = fmaf(0.5f, gb, g_y);
    }

#pragma unroll
    for (int off = 32; off > 0; off >>= 1) {
        dhq_x += __shfl_xor(dhq_x, off);
        dhq_y += __shfl_xor(dhq_y, off);
        g_x   += __shfl_xor(g_x, off);
        g_y   += __shfl_xor(g_y, off);
    }

    if (b == 0) {
        float* pO = p_out + (batch * NCP + a) * 2;
        float* qO = q_out + (batch * NCP + a) * 2;
        pO[0] = fmaf(DTF, dhq_x, pax);
        pO[1] = fmaf(DTF, dhq_y, pay);
        qO[0] = fmaf(-DTF, g_x, qax);
        qO[1] = fmaf(-DTF, g_y, qay);
    }
}

// ======================================================================
// Flow step 0: x == tpl, p == cp for ALL batches -> one kblock per (i,j),
// apply all 16 batches' q. Writes x^(1) into d_out. (R11 launch config.)
// ======================================================================
__global__ __launch_bounds__(256, 1)
void flow_step0(const float* __restrict__ tpl, const float* __restrict__ cp,
                const float* __restrict__ q0, float* __restrict__ out,
                const float* __restrict__ wt)
{
    int i = blockIdx.x * 4 + (threadIdx.x >> 6);
    int j = threadIdx.x & 63;

    float w[180];
    load_w(wt, j, w);

    float x0 = tpl[2 * i], x1 = tpl[2 * i + 1];
    float p0 = cp[2 * j],  p1 = cp[2 * j + 1];

    float M00, M01, M11;
    kblock(x0, x1, p0, p1, w, wt, M00, M01, M11);

    const float2* __restrict__ q = (const float2*)q0;
#pragma unroll
    for (int bt = 0; bt < BTS; ++bt) {
        float2 qq = q[bt * NCP + j];
        float vx = fmaf(M00, qq.x, M01 * qq.y);
        float vy = fmaf(M01, qq.x, M11 * qq.y);
#pragma unroll
        for (int off = 32; off > 0; off >>= 1) {
            vx += __shfl_xor(vx, off);
            vy += __shfl_xor(vy, off);
        }
        if (j == 0) {
            out[((size_t)bt * NTPL + i) * 2 + 0] = fmaf(DTF, vx, x0);
            out[((size_t)bt * NTPL + i) * 2 + 1] = fmaf(DTF, vy, x1);
        }
    }
}

// ======================================================================
// Flow steps 1..6: wave = (batch, i); lane = control point j. (R11 config.)
// ======================================================================
__global__ __launch_bounds__(256, 1)
void flow_rest(const float* __restrict__ p_hist, const float* __restrict__ q_hist,
               float* __restrict__ out, const float* __restrict__ wt)
{
    int unit = blockIdx.x * 4 + (threadIdx.x >> 6);
    int j = threadIdx.x & 63;
    int batch = unit >> 11;
    int i = unit & (NTPL - 1);

    float w[180];
    load_w(wt, j, w);

    const float2* __restrict__ ph = (const float2*)p_hist;
    const float2* __restrict__ qh = (const float2*)q_hist;

    size_t oidx = ((size_t)batch * NTPL + i) * 2;
    float x0 = out[oidx + 0];
    float x1 = out[oidx + 1];

#pragma unroll
    for (int s = 0; s < TSTEPS; ++s) {
        int idx = ((s + 1) * BTS + batch) * NCP + j;
        float2 P = ph[idx];
        float2 Q = qh[idx];
        float M00, M01, M11;
        kblock(x0, x1, P.x, P.y, w, wt, M00, M01, M11);
        float vx = fmaf(M00, Q.x, M01 * Q.y);
        float vy = fmaf(M01, Q.x, M11 * Q.y);
#pragma unroll
        for (int off = 32; off > 0; off >>= 1) {
            vx += __shfl_xor(vx, off);
            vy += __shfl_xor(vy, off);
        }
        x0 = fmaf(DTF, vx, x0);
        x1 = fmaf(DTF, vy, x1);
    }

    if (j == 0) {
        out[oidx + 0] = x0;
        out[oidx + 1] = x1;
    }
}

extern "C" void kernel_launch(void* const* d_in, const int* in_sizes, int n_in,
                              void* d_out, int out_size, void* d_ws, size_t ws_size,
                              hipStream_t stream)
{
    const float* q0  = (const float*)d_in[0];   // [16,64,2]
    const float* tpl = (const float*)d_in[1];   // [2048,2]
    const float* cp  = (const float*)d_in[2];   // [64,2]
    const float* W1  = (const float*)d_in[3];   // [4,10]
    const float* b1  = (const float*)d_in[4];   // [10]
    const float* W2  = (const float*)d_in[5];   // [10,10]
    const float* b2  = (const float*)d_in[6];   // [10]
    const float* W3  = (const float*)d_in[7];   // [10,3]
    const float* b3  = (const float*)d_in[8];   // [3]
    float* out = (float*)d_out;

    float* ws = (float*)d_ws;
    const int slab = BTS * NCP * 2;                      // 2048 floats / slice
    float* p_hist = ws;                                  // 7 slabs (slot 0 unused)
    float* q_hist = ws + (size_t)7 * slab;
    float* wt     = ws + (size_t)14 * slab;              // 193 floats

    shoot_step<<<BTS * NCP + 1, 64, 0, stream>>>(
        q0, cp, nullptr, nullptr,
        p_hist + (size_t)1 * slab, q_hist + (size_t)1 * slab,
        W1, b1, W2, b2, W3, b3, wt, 1);
    for (int s = 1; s < TSTEPS; ++s) {
        shoot_step<<<BTS * NCP, 64, 0, stream>>>(
            q0, cp,
            p_hist + (size_t)s * slab, q_hist + (size_t)s * slab,
            p_hist + (size_t)(s + 1) * slab, q_hist + (size_t)(s + 1) * slab,
            W1, b1, W2, b2, W3, b3, wt, 0);
    }

    flow_step0<<<NTPL / 4, 256, 0, stream>>>(tpl, cp, q0, out, wt);
    flow_rest<<<BTS * NTPL / 4, 256, 0, stream>>>(p_hist, q_hist, out, wt);
}

// Round 14
// 302.746 us; speedup vs baseline: 3.8069x; 1.1496x over previous
//
#include <hip/hip_runtime.h>

#define NCP    64
#define BTS    16
#define NTPL   2048
#define TSTEPS 6
#define DTF    0.2f                      // 1/(T-1)
#define L2E    1.4426950408889634f       // log2(e)

// ---------- fast scalar helpers ----------
__device__ __forceinline__ float fast_rcp(float x) { return __builtin_amdgcn_rcpf(x); }
__device__ __forceinline__ float fexp2(float x)    { return __builtin_amdgcn_exp2f(x); }
__device__ __forceinline__ float fast_tanh(float x) {        // shoot path
    float e = __expf(2.0f * x);
    return 1.0f - 2.0f * fast_rcp(1.0f + e);
}

// ======================================================================
// Single symmetrized 2x2 kernel block (plain sigmoid — R11-proven; sig4
// and Padé variants all regressed: trans ops are ~free on gfx950, total
// VALU inst count is what matters). Hot weights VGPR/shfl-resident.
// Local w layout: [0..39]=W1t [40..49]=b1t [50..149]=W2t
//                 [150..159]=C0 [160..169]=C1 [170..179]=C2
// Global wt layout: W1t[0..39] b1t[40..49] W2t[50..149] b2t[150..159]
//                   C0[160..169] C1[170..179] C2[180..189] b3t[190..192]
// ======================================================================
__device__ __forceinline__ void kblock(
    float x0, float x1, float p0, float p1,
    const float (&w)[180], const float* __restrict__ wt,
    float& M00, float& M01, float& M11)
{
    float ra[10], rb[10];
#pragma unroll
    for (int k = 0; k < 10; ++k) {
        float ta = fmaf(p1, w[30 + k],
                   fmaf(p0, w[20 + k],
                   fmaf(x1, w[10 + k],
                   fmaf(x0, w[k], w[40 + k]))));
        float tb = fmaf(x1, w[30 + k],
                   fmaf(x0, w[20 + k],
                   fmaf(p1, w[10 + k],
                   fmaf(p0, w[k], w[40 + k]))));
        ra[k] = fast_rcp(1.0f + fexp2(ta));
        rb[k] = fast_rcp(1.0f + fexp2(tb));
    }
    float ua[10], ub[10];
#pragma unroll
    for (int k = 0; k < 10; ++k) {
        float bb = wt[150 + k];          // b2t: cold, once per kblock
        ua[k] = fmaf(ra[0], w[50 + k], bb);
        ub[k] = fmaf(rb[0], w[50 + k], bb);
    }
#pragma unroll
    for (int c = 1; c < 10; ++c) {
#pragma unroll
        for (int k = 0; k < 10; ++k) {
            float ww = w[50 + c * 10 + k];
            ua[k] = fmaf(ra[c], ww, ua[k]);
            ub[k] = fmaf(rb[c], ww, ub[k]);
        }
    }
    float Oa = wt[190], Ob = wt[190];
    float T1a = wt[191], T1b = wt[191];
    float T2a = wt[192], T2b = wt[192];
#pragma unroll
    for (int c = 0; c < 10; ++c) {
        float r2a = fast_rcp(1.0f + fexp2(ua[c]));
        float r2b = fast_rcp(1.0f + fexp2(ub[c]));
        Oa  = fmaf(r2a, w[150 + c], Oa);   Ob  = fmaf(r2b, w[150 + c], Ob);
        T1a = fmaf(r2a, w[160 + c], T1a);  T1b = fmaf(r2b, w[160 + c], T1b);
        T2a = fmaf(r2a, w[170 + c], T2a);  T2b = fmaf(r2b, w[170 + c], T2b);
    }
    M00 = fexp2(T1a) + fexp2(T1b);   // 0.5*(exp(o1a)+exp(o1b))
    M01 = Oa + Ob;
    M11 = fexp2(T2a) + fexp2(T2b);
}

// ======================================================================
// Dual kernel block: TWO template points (xa, xb) vs one control point p.
// 4 interleaved MLP streams -> 2x ILP per lane (hides FMA/trans latency
// at the ~1.75 waves/SIMD occupancy this kernel runs at) and every
// fetched weight serves 4 FMAs (amortizes shfl/bpermute refetch).
// ======================================================================
__device__ __forceinline__ void kblock2(
    float xa0, float xa1, float xb0, float xb1, float p0, float p1,
    const float (&w)[180], const float* __restrict__ wt,
    float& Ma00, float& Ma01, float& Ma11,
    float& Mb00, float& Mb01, float& Mb11)
{
    float r1[10], r2[10], r3[10], r4[10];
#pragma unroll
    for (int k = 0; k < 10; ++k) {
        float w0 = w[k], w1 = w[10 + k], w2 = w[20 + k], w3 = w[30 + k];
        float bb = w[40 + k];
        float t1 = fmaf(p1, w3, fmaf(p0, w2, fmaf(xa1, w1, fmaf(xa0, w0, bb))));
        float t2 = fmaf(xa1, w3, fmaf(xa0, w2, fmaf(p1, w1, fmaf(p0, w0, bb))));
        float t3 = fmaf(p1, w3, fmaf(p0, w2, fmaf(xb1, w1, fmaf(xb0, w0, bb))));
        float t4 = fmaf(xb1, w3, fmaf(xb0, w2, fmaf(p1, w1, fmaf(p0, w0, bb))));
        r1[k] = fast_rcp(1.0f + fexp2(t1));
        r2[k] = fast_rcp(1.0f + fexp2(t2));
        r3[k] = fast_rcp(1.0f + fexp2(t3));
        r4[k] = fast_rcp(1.0f + fexp2(t4));
    }
    float u1[10], u2[10], u3[10], u4[10];
#pragma unroll
    for (int k = 0; k < 10; ++k) {
        float bb = wt[150 + k];
        float ww = w[50 + k];
        u1[k] = fmaf(r1[0], ww, bb);
        u2[k] = fmaf(r2[0], ww, bb);
        u3[k] = fmaf(r3[0], ww, bb);
        u4[k] = fmaf(r4[0], ww, bb);
    }
#pragma unroll
    for (int c = 1; c < 10; ++c) {
#pragma unroll
        for (int k = 0; k < 10; ++k) {
            float ww = w[50 + c * 10 + k];
            u1[k] = fmaf(r1[c], ww, u1[k]);
            u2[k] = fmaf(r2[c], ww, u2[k]);
            u3[k] = fmaf(r3[c], ww, u3[k]);
            u4[k] = fmaf(r4[c], ww, u4[k]);
        }
    }
    float O1 = wt[190], O2 = O1, O3 = O1, O4 = O1;
    float A1 = wt[191], A2 = A1, A3 = A1, A4 = A1;
    float B1 = wt[192], B2 = B1, B3 = B1, B4 = B1;
#pragma unroll
    for (int c = 0; c < 10; ++c) {
        float g1 = fast_rcp(1.0f + fexp2(u1[c]));
        float g2 = fast_rcp(1.0f + fexp2(u2[c]));
        float g3 = fast_rcp(1.0f + fexp2(u3[c]));
        float g4 = fast_rcp(1.0f + fexp2(u4[c]));
        float c0 = w[150 + c], c1 = w[160 + c], c2 = w[170 + c];
        O1 = fmaf(g1, c0, O1); O2 = fmaf(g2, c0, O2);
        O3 = fmaf(g3, c0, O3); O4 = fmaf(g4, c0, O4);
        A1 = fmaf(g1, c1, A1); A2 = fmaf(g2, c1, A2);
        A3 = fmaf(g3, c1, A3); A4 = fmaf(g4, c1, A4);
        B1 = fmaf(g1, c2, B1); B2 = fmaf(g2, c2, B2);
        B3 = fmaf(g3, c2, B3); B4 = fmaf(g4, c2, B4);
    }
    Ma00 = fexp2(A1) + fexp2(A2);
    Ma01 = O1 + O2;
    Ma11 = fexp2(B1) + fexp2(B2);
    Mb00 = fexp2(A3) + fexp2(A4);
    Mb01 = O3 + O4;
    Mb11 = fexp2(B3) + fexp2(B4);
}

// Load the 180 hot weights: 3 lane-strided vector loads + __shfl distribute.
__device__ __forceinline__ void load_w(const float* __restrict__ wt,
                                       int lane, float (&w)[180])
{
    float c0 = wt[lane];            // wt[0..63]
    float c1 = wt[64 + lane];       // wt[64..127]
    float c2 = wt[128 + lane];      // wt[128..191]
#pragma unroll
    for (int t = 0; t < 180; ++t) {
        int src = (t < 150) ? t : (t + 10);   // skip b2t at wt[150..159]
        int ch = src >> 6, ix = src & 63;
        float v = (ch == 0) ? c0 : (ch == 1) ? c1 : c2;
        w[t] = __shfl(v, ix);
    }
}

// ======================================================================
// One symplectic shooting step (R2/R6/R9-proven). Grid 1024(+1 on first).
// first!=0: read p from cp / q from q0; block 1024 folds wt instead.
// ======================================================================
__global__ __launch_bounds__(64, 1)
void shoot_step(const float* __restrict__ q0, const float* __restrict__ cp,
                const float* __restrict__ p_in, const float* __restrict__ q_in,
                float* __restrict__ p_out, float* __restrict__ q_out,
                const float* __restrict__ W1, const float* __restrict__ b1,
                const float* __restrict__ W2, const float* __restrict__ b2,
                const float* __restrict__ W3, const float* __restrict__ b3,
                float* __restrict__ wt, int first)
{
    int blk = blockIdx.x;
    if (first && blk == BTS * NCP) {
        int t = threadIdx.x;
        if (t < 40) wt[t] = 2.0f * L2E * W1[t];
        if (t < 10) wt[40 + t] = 2.0f * L2E * b1[t];
        for (int i = t; i < 100; i += 64) wt[50 + i] = -4.0f * L2E * W2[i];
        if (t < 10) {
            float s = b2[t];
            for (int c = 0; c < 10; ++c) s += W2[c * 10 + t];
            wt[150 + t] = 2.0f * L2E * s;                 // b2''
            wt[160 + t] = -W3[t * 3 + 0];                 // C0 (0.5 * -2)
            wt[170 + t] = -2.0f * L2E * W3[t * 3 + 1];    // C1
            wt[180 + t] = -2.0f * L2E * W3[t * 3 + 2];    // C2
        }
        if (t < 3) {
            float s = b3[t];
            for (int c = 0; c < 10; ++c) s += W3[c * 3 + t];
            wt[190 + t] = (t == 0) ? 0.5f * s : fmaf(L2E, s, -1.0f);
        }
        return;
    }

    int batch = blk >> 6;
    int a = blk & (NCP - 1);
    int b = threadIdx.x;

    float pax, pay, qax, qay, pbx, pby, qbx, qby;
    if (first) {
        pax = cp[2 * a]; pay = cp[2 * a + 1];
        pbx = cp[2 * b]; pby = cp[2 * b + 1];
        qax = q0[(batch * NCP + a) * 2 + 0]; qay = q0[(batch * NCP + a) * 2 + 1];
        qbx = q0[(batch * NCP + b) * 2 + 0]; qby = q0[(batch * NCP + b) * 2 + 1];
    } else {
        const float* pB = p_in + batch * NCP * 2;
        const float* qB = q_in + batch * NCP * 2;
        pax = pB[a * 2 + 0]; pay = pB[a * 2 + 1];
        qax = qB[a * 2 + 0]; qay = qB[a * 2 + 1];
        pbx = pB[b * 2 + 0]; pby = pB[b * 2 + 1];
        qbx = qB[b * 2 + 0]; qby = qB[b * 2 + 1];
    }

    float dhq_x = 0.f, dhq_y = 0.f;
    float g_x = 0.f, g_y = 0.f;
    float cross = fmaf(qax, qby, qay * qbx);

#pragma unroll
    for (int e = 0; e < 2; ++e) {
        float z0 = e ? pbx : pax;
        float z1 = e ? pby : pay;
        float z2 = e ? pax : pbx;
        float z3 = e ? pay : pby;

        float h1[10];
#pragma unroll
        for (int k = 0; k < 10; ++k) {
            float u = fmaf(z3, W1[30 + k],
                      fmaf(z2, W1[20 + k],
                      fmaf(z1, W1[10 + k],
                      fmaf(z0, W1[k], b1[k]))));
            h1[k] = fast_tanh(u);
        }
        float u2[10];
#pragma unroll
        for (int k = 0; k < 10; ++k) u2[k] = b2[k];
#pragma unroll
        for (int c = 0; c < 10; ++c) {
#pragma unroll
            for (int k = 0; k < 10; ++k) u2[k] = fmaf(h1[c], W2[c * 10 + k], u2[k]);
        }
        float h2[10];
        float o0 = b3[0], o1 = b3[1], o2 = b3[2];
#pragma unroll
        for (int c = 0; c < 10; ++c) {
            h2[c] = fast_tanh(u2[c]);
            o0 = fmaf(h2[c], W3[c * 3 + 0], o0);
            o1 = fmaf(h2[c], W3[c * 3 + 1], o1);
            o2 = fmaf(h2[c], W3[c * 3 + 2], o2);
        }
        float e1 = __expf(o1), e2 = __expf(o2);

        dhq_x = fmaf(0.5f, fmaf(e1, qbx, o0 * qby), dhq_x);
        dhq_y = fmaf(0.5f, fmaf(o0, qbx, e2 * qby), dhq_y);

        float d0 = cross;
        float d1 = e1 * qax * qbx;
        float d2 = e2 * qay * qby;

        float du2[10];
#pragma unroll
        for (int c = 0; c < 10; ++c) {
            float dh2 = fmaf(W3[c * 3 + 0], d0,
                        fmaf(W3[c * 3 + 1], d1, W3[c * 3 + 2] * d2));
            du2[c] = dh2 * (1.0f - h2[c] * h2[c]);
        }
        float du1[10];
#pragma unroll
        for (int c = 0; c < 10; ++c) {
            float dh1 = 0.f;
#pragma unroll
            for (int k = 0; k < 10; ++k) dh1 = fmaf(W2[c * 10 + k], du2[k], dh1);
            du1[c] = dh1 * (1.0f - h1[c] * h1[c]);
        }
        int c0 = e ? 2 : 0;
        float ga = 0.f, gb = 0.f;
#pragma unroll
        for (int k = 0; k < 10; ++k) {
            ga = fmaf(W1[(0 + c0) * 10 + k], du1[k], ga);
            gb = fmaf(W1[(1 + c0) * 10 + k], du1[k], gb);
        }
        g_x = fmaf(0.5f, ga, g_x);
        g_y = fmaf(0.5f, gb, g_y);
    }

#pragma unroll
    for (int off = 32; off > 0; off >>= 1) {
        dhq_x += __shfl_xor(dhq_x, off);
        dhq_y += __shfl_xor(dhq_y, off);
        g_x   += __shfl_xor(g_x, off);
        g_y   += __shfl_xor(g_y, off);
    }

    if (b == 0) {
        float* pO = p_out + (batch * NCP + a) * 2;
        float* qO = q_out + (batch * NCP + a) * 2;
        pO[0] = fmaf(DTF, dhq_x, pax);
        pO[1] = fmaf(DTF, dhq_y, pay);
        qO[0] = fmaf(-DTF, g_x, qax);
        qO[1] = fmaf(-DTF, g_y, qay);
    }
}

// ======================================================================
// Flow step 0: x == tpl, p == cp for ALL batches -> one kblock per (i,j),
// apply all 16 batches' q. Writes x^(1) into d_out.
// ======================================================================
__global__ __launch_bounds__(256, 1)
void flow_step0(const float* __restrict__ tpl, const float* __restrict__ cp,
                const float* __restrict__ q0, float* __restrict__ out,
                const float* __restrict__ wt)
{
    int i = blockIdx.x * 4 + (threadIdx.x >> 6);
    int j = threadIdx.x & 63;

    float w[180];
    load_w(wt, j, w);

    float x0 = tpl[2 * i], x1 = tpl[2 * i + 1];
    float p0 = cp[2 * j],  p1 = cp[2 * j + 1];

    float M00, M01, M11;
    kblock(x0, x1, p0, p1, w, wt, M00, M01, M11);

    const float2* __restrict__ q = (const float2*)q0;
#pragma unroll
    for (int bt = 0; bt < BTS; ++bt) {
        float2 qq = q[bt * NCP + j];
        float vx = fmaf(M00, qq.x, M01 * qq.y);
        float vy = fmaf(M01, qq.x, M11 * qq.y);
#pragma unroll
        for (int off = 32; off > 0; off >>= 1) {
            vx += __shfl_xor(vx, off);
            vy += __shfl_xor(vy, off);
        }
        if (j == 0) {
            out[((size_t)bt * NTPL + i) * 2 + 0] = fmaf(DTF, vx, x0);
            out[((size_t)bt * NTPL + i) * 2 + 1] = fmaf(DTF, vy, x1);
        }
    }
}

// ======================================================================
// Flow steps 1..6: wave = (batch, i-pair); lane = control point j.
// Two template points per wave (kblock2) for 2x per-lane ILP.
// ======================================================================
__global__ __launch_bounds__(256, 1)
void flow_rest(const float* __restrict__ p_hist, const float* __restrict__ q_hist,
               float* __restrict__ out, const float* __restrict__ wt)
{
    int wid = blockIdx.x * 4 + (threadIdx.x >> 6);   // 0..BTS*NTPL/2-1
    int j = threadIdx.x & 63;
    int u = wid * 2;                                  // even unit
    int batch = u >> 11;
    int i1 = u & (NTPL - 1);                          // even, i2 = i1+1 same batch
    
    float w[180];
    load_w(wt, j, w);

    const float2* __restrict__ ph = (const float2*)p_hist;
    const float2* __restrict__ qh = (const float2*)q_hist;

    size_t o1 = ((size_t)batch * NTPL + i1) * 2;
    size_t o2 = o1 + 2;
    float xa0 = out[o1 + 0], xa1 = out[o1 + 1];
    float xb0 = out[o2 + 0], xb1 = out[o2 + 1];

#pragma unroll
    for (int s = 0; s < TSTEPS; ++s) {
        int idx = ((s + 1) * BTS + batch) * NCP + j;
        float2 P = ph[idx];
        float2 Q = qh[idx];
        float Ma00, Ma01, Ma11, Mb00, Mb01, Mb11;
        kblock2(xa0, xa1, xb0, xb1, P.x, P.y, w, wt,
                Ma00, Ma01, Ma11, Mb00, Mb01, Mb11);
        float vax = fmaf(Ma00, Q.x, Ma01 * Q.y);
        float vay = fmaf(Ma01, Q.x, Ma11 * Q.y);
        float vbx = fmaf(Mb00, Q.x, Mb01 * Q.y);
        float vby = fmaf(Mb01, Q.x, Mb11 * Q.y);
#pragma unroll
        for (int off = 32; off > 0; off >>= 1) {
            vax += __shfl_xor(vax, off);
            vay += __shfl_xor(vay, off);
            vbx += __shfl_xor(vbx, off);
            vby += __shfl_xor(vby, off);
        }
        xa0 = fmaf(DTF, vax, xa0);
        xa1 = fmaf(DTF, vay, xa1);
        xb0 = fmaf(DTF, vbx, xb0);
        xb1 = fmaf(DTF, vby, xb1);
    }

    if (j == 0) {
        out[o1 + 0] = xa0;
        out[o1 + 1] = xa1;
        out[o2 + 0] = xb0;
        out[o2 + 1] = xb1;
    }
}

extern "C" void kernel_launch(void* const* d_in, const int* in_sizes, int n_in,
                              void* d_out, int out_size, void* d_ws, size_t ws_size,
                              hipStream_t stream)
{
    const float* q0  = (const float*)d_in[0];   // [16,64,2]
    const float* tpl = (const float*)d_in[1];   // [2048,2]
    const float* cp  = (const float*)d_in[2];   // [64,2]
    const float* W1  = (const float*)d_in[3];   // [4,10]
    const float* b1  = (const float*)d_in[4];   // [10]
    const float* W2  = (const float*)d_in[5];   // [10,10]
    const float* b2  = (const float*)d_in[6];   // [10]
    const float* W3  = (const float*)d_in[7];   // [10,3]
    const float* b3  = (const float*)d_in[8];   // [3]
    float* out = (float*)d_out;

    float* ws = (float*)d_ws;
    const int slab = BTS * NCP * 2;                      // 2048 floats / slice
    float* p_hist = ws;                                  // 7 slabs (slot 0 unused)
    float* q_hist = ws + (size_t)7 * slab;
    float* wt     = ws + (size_t)14 * slab;              // 193 floats

    shoot_step<<<BTS * NCP + 1, 64, 0, stream>>>(
        q0, cp, nullptr, nullptr,
        p_hist + (size_t)1 * slab, q_hist + (size_t)1 * slab,
        W1, b1, W2, b2, W3, b3, wt, 1);
    for (int s = 1; s < TSTEPS; ++s) {
        shoot_step<<<BTS * NCP, 64, 0, stream>>>(
            q0, cp,
            p_hist + (size_t)s * slab, q_hist + (size_t)s * slab,
            p_hist + (size_t)(s + 1) * slab, q_hist + (size_t)(s + 1) * slab,
            W1, b1, W2, b2, W3, b3, wt, 0);
    }

    flow_step0<<<NTPL / 4, 256, 0, stream>>>(tpl, cp, q0, out, wt);
    flow_rest<<<BTS * NTPL / 8, 256, 0, stream>>>(p_hist, q_hist, out, wt);
}

// Round 15
// 300.188 us; speedup vs baseline: 3.8393x; 1.0085x over previous
//
#include <hip/hip_runtime.h>

#define NCP    64
#define BTS    16
#define NTPL   2048
#define TSTEPS 6
#define DTF    0.2f                      // 1/(T-1)
#define L2E    1.4426950408889634f       // log2(e)

// ---------- fast scalar helpers ----------
__device__ __forceinline__ float fast_rcp(float x) { return __builtin_amdgcn_rcpf(x); }
__device__ __forceinline__ float fexp2(float x)    { return __builtin_amdgcn_exp2f(x); }
__device__ __forceinline__ float fast_tanh(float x) {        // shoot path
    float e = __expf(2.0f * x);
    return 1.0f - 2.0f * fast_rcp(1.0f + e);
}

// ======================================================================
// Single symmetrized 2x2 kernel block (plain sigmoid — R11-proven).
// Local w layout: [0..39]=W1t [40..49]=b1t [50..149]=W2t
//                 [150..159]=C0 [160..169]=C1 [170..179]=C2
// Global wt layout: W1t[0..39] b1t[40..49] W2t[50..149] b2t[150..159]
//                   C0[160..169] C1[170..179] C2[180..189] b3t[190..192]
// ======================================================================
__device__ __forceinline__ void kblock(
    float x0, float x1, float p0, float p1,
    const float (&w)[180], const float* __restrict__ wt,
    float& M00, float& M01, float& M11)
{
    float ra[10], rb[10];
#pragma unroll
    for (int k = 0; k < 10; ++k) {
        float ta = fmaf(p1, w[30 + k],
                   fmaf(p0, w[20 + k],
                   fmaf(x1, w[10 + k],
                   fmaf(x0, w[k], w[40 + k]))));
        float tb = fmaf(x1, w[30 + k],
                   fmaf(x0, w[20 + k],
                   fmaf(p1, w[10 + k],
                   fmaf(p0, w[k], w[40 + k]))));
        ra[k] = fast_rcp(1.0f + fexp2(ta));
        rb[k] = fast_rcp(1.0f + fexp2(tb));
    }
    float ua[10], ub[10];
#pragma unroll
    for (int k = 0; k < 10; ++k) {
        float bb = wt[150 + k];
        ua[k] = fmaf(ra[0], w[50 + k], bb);
        ub[k] = fmaf(rb[0], w[50 + k], bb);
    }
#pragma unroll
    for (int c = 1; c < 10; ++c) {
#pragma unroll
        for (int k = 0; k < 10; ++k) {
            float ww = w[50 + c * 10 + k];
            ua[k] = fmaf(ra[c], ww, ua[k]);
            ub[k] = fmaf(rb[c], ww, ub[k]);
        }
    }
    float Oa = wt[190], Ob = wt[190];
    float T1a = wt[191], T1b = wt[191];
    float T2a = wt[192], T2b = wt[192];
#pragma unroll
    for (int c = 0; c < 10; ++c) {
        float r2a = fast_rcp(1.0f + fexp2(ua[c]));
        float r2b = fast_rcp(1.0f + fexp2(ub[c]));
        Oa  = fmaf(r2a, w[150 + c], Oa);   Ob  = fmaf(r2b, w[150 + c], Ob);
        T1a = fmaf(r2a, w[160 + c], T1a);  T1b = fmaf(r2b, w[160 + c], T1b);
        T2a = fmaf(r2a, w[170 + c], T2a);  T2b = fmaf(r2b, w[170 + c], T2b);
    }
    M00 = fexp2(T1a) + fexp2(T1b);
    M01 = Oa + Ob;
    M11 = fexp2(T2a) + fexp2(T2b);
}

// ======================================================================
// Quad kernel block: FOUR template points vs one control point p.
// 8 interleaved MLP streams -> deep per-lane ILP (hides bpermute/FMA
// latency at ~1.75 waves/SIMD) and every materialized weight feeds 8
// FMAs. Peak live ~190 floats: REQUIRES launch_bounds(256,1) (256-VGPR
// budget; at 128 this spills catastrophically — R12 lesson).
// ======================================================================
__device__ __forceinline__ void kblock4(
    const float (&x0)[4], const float (&x1)[4], float p0, float p1,
    const float (&w)[180], const float* __restrict__ wt,
    float (&M00)[4], float (&M01)[4], float (&M11)[4])
{
    float r[8][10];
#pragma unroll
    for (int k = 0; k < 10; ++k) {
        float w0 = w[k], w1 = w[10 + k], w2 = w[20 + k], w3 = w[30 + k];
        float bb = w[40 + k];
#pragma unroll
        for (int m = 0; m < 4; ++m) {
            float ta = fmaf(p1, w3, fmaf(p0, w2,
                       fmaf(x1[m], w1, fmaf(x0[m], w0, bb))));
            float tb = fmaf(x1[m], w3, fmaf(x0[m], w2,
                       fmaf(p1, w1, fmaf(p0, w0, bb))));
            r[2 * m][k]     = fast_rcp(1.0f + fexp2(ta));
            r[2 * m + 1][k] = fast_rcp(1.0f + fexp2(tb));
        }
    }
    float u[8][10];
#pragma unroll
    for (int k = 0; k < 10; ++k) {
        float bb = wt[150 + k];
        float ww = w[50 + k];
#pragma unroll
        for (int s = 0; s < 8; ++s) u[s][k] = fmaf(r[s][0], ww, bb);
    }
#pragma unroll
    for (int c = 1; c < 10; ++c) {
#pragma unroll
        for (int k = 0; k < 10; ++k) {
            float ww = w[50 + c * 10 + k];
#pragma unroll
            for (int s = 0; s < 8; ++s) u[s][k] = fmaf(r[s][c], ww, u[s][k]);
        }
    }
    float O[8], A[8], B[8];
#pragma unroll
    for (int s = 0; s < 8; ++s) { O[s] = wt[190]; A[s] = wt[191]; B[s] = wt[192]; }
#pragma unroll
    for (int c = 0; c < 10; ++c) {
        float c0 = w[150 + c], c1 = w[160 + c], c2 = w[170 + c];
#pragma unroll
        for (int s = 0; s < 8; ++s) {
            float g = fast_rcp(1.0f + fexp2(u[s][c]));
            O[s] = fmaf(g, c0, O[s]);
            A[s] = fmaf(g, c1, A[s]);
            B[s] = fmaf(g, c2, B[s]);
        }
    }
#pragma unroll
    for (int m = 0; m < 4; ++m) {
        M00[m] = fexp2(A[2 * m]) + fexp2(A[2 * m + 1]);
        M01[m] = O[2 * m] + O[2 * m + 1];
        M11[m] = fexp2(B[2 * m]) + fexp2(B[2 * m + 1]);
    }
}

// Load the 180 hot weights: 3 lane-strided vector loads + __shfl distribute.
__device__ __forceinline__ void load_w(const float* __restrict__ wt,
                                       int lane, float (&w)[180])
{
    float c0 = wt[lane];            // wt[0..63]
    float c1 = wt[64 + lane];       // wt[64..127]
    float c2 = wt[128 + lane];      // wt[128..191]
#pragma unroll
    for (int t = 0; t < 180; ++t) {
        int src = (t < 150) ? t : (t + 10);   // skip b2t at wt[150..159]
        int ch = src >> 6, ix = src & 63;
        float v = (ch == 0) ? c0 : (ch == 1) ? c1 : c2;
        w[t] = __shfl(v, ix);
    }
}

// ======================================================================
// One symplectic shooting step (R2/R6/R9-proven). Grid 1024(+1 on first).
// first!=0: read p from cp / q from q0; block 1024 folds wt instead.
// ======================================================================
__global__ __launch_bounds__(64, 1)
void shoot_step(const float* __restrict__ q0, const float* __restrict__ cp,
                const float* __restrict__ p_in, const float* __restrict__ q_in,
                float* __restrict__ p_out, float* __restrict__ q_out,
                const float* __restrict__ W1, const float* __restrict__ b1,
                const float* __restrict__ W2, const float* __restrict__ b2,
                const float* __restrict__ W3, const float* __restrict__ b3,
                float* __restrict__ wt, int first)
{
    int blk = blockIdx.x;
    if (first && blk == BTS * NCP) {
        int t = threadIdx.x;
        if (t < 40) wt[t] = 2.0f * L2E * W1[t];
        if (t < 10) wt[40 + t] = 2.0f * L2E * b1[t];
        for (int i = t; i < 100; i += 64) wt[50 + i] = -4.0f * L2E * W2[i];
        if (t < 10) {
            float s = b2[t];
            for (int c = 0; c < 10; ++c) s += W2[c * 10 + t];
            wt[150 + t] = 2.0f * L2E * s;                 // b2''
            wt[160 + t] = -W3[t * 3 + 0];                 // C0 (0.5 * -2)
            wt[170 + t] = -2.0f * L2E * W3[t * 3 + 1];    // C1
            wt[180 + t] = -2.0f * L2E * W3[t * 3 + 2];    // C2
        }
        if (t < 3) {
            float s = b3[t];
            for (int c = 0; c < 10; ++c) s += W3[c * 3 + t];
            wt[190 + t] = (t == 0) ? 0.5f * s : fmaf(L2E, s, -1.0f);
        }
        return;
    }

    int batch = blk >> 6;
    int a = blk & (NCP - 1);
    int b = threadIdx.x;

    float pax, pay, qax, qay, pbx, pby, qbx, qby;
    if (first) {
        pax = cp[2 * a]; pay = cp[2 * a + 1];
        pbx = cp[2 * b]; pby = cp[2 * b + 1];
        qax = q0[(batch * NCP + a) * 2 + 0]; qay = q0[(batch * NCP + a) * 2 + 1];
        qbx = q0[(batch * NCP + b) * 2 + 0]; qby = q0[(batch * NCP + b) * 2 + 1];
    } else {
        const float* pB = p_in + batch * NCP * 2;
        const float* qB = q_in + batch * NCP * 2;
        pax = pB[a * 2 + 0]; pay = pB[a * 2 + 1];
        qax = qB[a * 2 + 0]; qay = qB[a * 2 + 1];
        pbx = pB[b * 2 + 0]; pby = pB[b * 2 + 1];
        qbx = qB[b * 2 + 0]; qby = qB[b * 2 + 1];
    }

    float dhq_x = 0.f, dhq_y = 0.f;
    float g_x = 0.f, g_y = 0.f;
    float cross = fmaf(qax, qby, qay * qbx);

#pragma unroll
    for (int e = 0; e < 2; ++e) {
        float z0 = e ? pbx : pax;
        float z1 = e ? pby : pay;
        float z2 = e ? pax : pbx;
        float z3 = e ? pay : pby;

        float h1[10];
#pragma unroll
        for (int k = 0; k < 10; ++k) {
            float u = fmaf(z3, W1[30 + k],
                      fmaf(z2, W1[20 + k],
                      fmaf(z1, W1[10 + k],
                      fmaf(z0, W1[k], b1[k]))));
            h1[k] = fast_tanh(u);
        }
        float u2[10];
#pragma unroll
        for (int k = 0; k < 10; ++k) u2[k] = b2[k];
#pragma unroll
        for (int c = 0; c < 10; ++c) {
#pragma unroll
            for (int k = 0; k < 10; ++k) u2[k] = fmaf(h1[c], W2[c * 10 + k], u2[k]);
        }
        float h2[10];
        float o0 = b3[0], o1 = b3[1], o2 = b3[2];
#pragma unroll
        for (int c = 0; c < 10; ++c) {
            h2[c] = fast_tanh(u2[c]);
            o0 = fmaf(h2[c], W3[c * 3 + 0], o0);
            o1 = fmaf(h2[c], W3[c * 3 + 1], o1);
            o2 = fmaf(h2[c], W3[c * 3 + 2], o2);
        }
        float e1 = __expf(o1), e2 = __expf(o2);

        dhq_x = fmaf(0.5f, fmaf(e1, qbx, o0 * qby), dhq_x);
        dhq_y = fmaf(0.5f, fmaf(o0, qbx, e2 * qby), dhq_y);

        float d0 = cross;
        float d1 = e1 * qax * qbx;
        float d2 = e2 * qay * qby;

        float du2[10];
#pragma unroll
        for (int c = 0; c < 10; ++c) {
            float dh2 = fmaf(W3[c * 3 + 0], d0,
                        fmaf(W3[c * 3 + 1], d1, W3[c * 3 + 2] * d2));
            du2[c] = dh2 * (1.0f - h2[c] * h2[c]);
        }
        float du1[10];
#pragma unroll
        for (int c = 0; c < 10; ++c) {
            float dh1 = 0.f;
#pragma unroll
            for (int k = 0; k < 10; ++k) dh1 = fmaf(W2[c * 10 + k], du2[k], dh1);
            du1[c] = dh1 * (1.0f - h1[c] * h1[c]);
        }
        int c0 = e ? 2 : 0;
        float ga = 0.f, gb = 0.f;
#pragma unroll
        for (int k = 0; k < 10; ++k) {
            ga = fmaf(W1[(0 + c0) * 10 + k], du1[k], ga);
            gb = fmaf(W1[(1 + c0) * 10 + k], du1[k], gb);
        }
        g_x = fmaf(0.5f, ga, g_x);
        g_y = fmaf(0.5f, gb, g_y);
    }

#pragma unroll
    for (int off = 32; off > 0; off >>= 1) {
        dhq_x += __shfl_xor(dhq_x, off);
        dhq_y += __shfl_xor(dhq_y, off);
        g_x   += __shfl_xor(g_x, off);
        g_y   += __shfl_xor(g_y, off);
    }

    if (b == 0) {
        float* pO = p_out + (batch * NCP + a) * 2;
        float* qO = q_out + (batch * NCP + a) * 2;
        pO[0] = fmaf(DTF, dhq_x, pax);
        pO[1] = fmaf(DTF, dhq_y, pay);
        qO[0] = fmaf(-DTF, g_x, qax);
        qO[1] = fmaf(-DTF, g_y, qay);
    }
}

// ======================================================================
// Flow step 0: x == tpl, p == cp for ALL batches -> one kblock per (i,j),
// apply all 16 batches' q. Writes x^(1) into d_out.
// ======================================================================
__global__ __launch_bounds__(256, 1)
void flow_step0(const float* __restrict__ tpl, const float* __restrict__ cp,
                const float* __restrict__ q0, float* __restrict__ out,
                const float* __restrict__ wt)
{
    int i = blockIdx.x * 4 + (threadIdx.x >> 6);
    int j = threadIdx.x & 63;

    float w[180];
    load_w(wt, j, w);

    float x0 = tpl[2 * i], x1 = tpl[2 * i + 1];
    float p0 = cp[2 * j],  p1 = cp[2 * j + 1];

    float M00, M01, M11;
    kblock(x0, x1, p0, p1, w, wt, M00, M01, M11);

    const float2* __restrict__ q = (const float2*)q0;
#pragma unroll
    for (int bt = 0; bt < BTS; ++bt) {
        float2 qq = q[bt * NCP + j];
        float vx = fmaf(M00, qq.x, M01 * qq.y);
        float vy = fmaf(M01, qq.x, M11 * qq.y);
#pragma unroll
        for (int off = 32; off > 0; off >>= 1) {
            vx += __shfl_xor(vx, off);
            vy += __shfl_xor(vy, off);
        }
        if (j == 0) {
            out[((size_t)bt * NTPL + i) * 2 + 0] = fmaf(DTF, vx, x0);
            out[((size_t)bt * NTPL + i) * 2 + 1] = fmaf(DTF, vy, x1);
        }
    }
}

// ======================================================================
// Flow steps 1..6: wave = (batch, 4 template points); lane = cp j.
// kblock4: 8 interleaved MLP streams per lane.
// ======================================================================
__global__ __launch_bounds__(256, 1)
void flow_rest(const float* __restrict__ p_hist, const float* __restrict__ q_hist,
               float* __restrict__ out, const float* __restrict__ wt)
{
    int wid = blockIdx.x * 4 + (threadIdx.x >> 6);   // 0..BTS*NTPL/4-1
    int j = threadIdx.x & 63;
    int u0 = wid * 4;
    int batch = u0 >> 11;
    int i0 = u0 & (NTPL - 1);                        // i0..i0+3, same batch

    float w[180];
    load_w(wt, j, w);

    const float2* __restrict__ ph = (const float2*)p_hist;
    const float2* __restrict__ qh = (const float2*)q_hist;

    size_t ob = ((size_t)batch * NTPL + i0) * 2;
    float x0[4], x1[4];
#pragma unroll
    for (int m = 0; m < 4; ++m) {
        x0[m] = out[ob + 2 * m];
        x1[m] = out[ob + 2 * m + 1];
    }

#pragma unroll
    for (int s = 0; s < TSTEPS; ++s) {
        int idx = ((s + 1) * BTS + batch) * NCP + j;
        float2 P = ph[idx];
        float2 Q = qh[idx];
        float M00[4], M01[4], M11[4];
        kblock4(x0, x1, P.x, P.y, w, wt, M00, M01, M11);
        float vx[4], vy[4];
#pragma unroll
        for (int m = 0; m < 4; ++m) {
            vx[m] = fmaf(M00[m], Q.x, M01[m] * Q.y);
            vy[m] = fmaf(M01[m], Q.x, M11[m] * Q.y);
        }
#pragma unroll
        for (int off = 32; off > 0; off >>= 1) {
#pragma unroll
            for (int m = 0; m < 4; ++m) {
                vx[m] += __shfl_xor(vx[m], off);
                vy[m] += __shfl_xor(vy[m], off);
            }
        }
#pragma unroll
        for (int m = 0; m < 4; ++m) {
            x0[m] = fmaf(DTF, vx[m], x0[m]);
            x1[m] = fmaf(DTF, vy[m], x1[m]);
        }
    }

    if (j == 0) {
#pragma unroll
        for (int m = 0; m < 4; ++m) {
            out[ob + 2 * m]     = x0[m];
            out[ob + 2 * m + 1] = x1[m];
        }
    }
}

extern "C" void kernel_launch(void* const* d_in, const int* in_sizes, int n_in,
                              void* d_out, int out_size, void* d_ws, size_t ws_size,
                              hipStream_t stream)
{
    const float* q0  = (const float*)d_in[0];   // [16,64,2]
    const float* tpl = (const float*)d_in[1];   // [2048,2]
    const float* cp  = (const float*)d_in[2];   // [64,2]
    const float* W1  = (const float*)d_in[3];   // [4,10]
    const float* b1  = (const float*)d_in[4];   // [10]
    const float* W2  = (const float*)d_in[5];   // [10,10]
    const float* b2  = (const float*)d_in[6];   // [10]
    const float* W3  = (const float*)d_in[7];   // [10,3]
    const float* b3  = (const float*)d_in[8];   // [3]
    float* out = (float*)d_out;

    float* ws = (float*)d_ws;
    const int slab = BTS * NCP * 2;                      // 2048 floats / slice
    float* p_hist = ws;                                  // 7 slabs (slot 0 unused)
    float* q_hist = ws + (size_t)7 * slab;
    float* wt     = ws + (size_t)14 * slab;              // 193 floats

    shoot_step<<<BTS * NCP + 1, 64, 0, stream>>>(
        q0, cp, nullptr, nullptr,
        p_hist + (size_t)1 * slab, q_hist + (size_t)1 * slab,
        W1, b1, W2, b2, W3, b3, wt, 1);
    for (int s = 1; s < TSTEPS; ++s) {
        shoot_step<<<BTS * NCP, 64, 0, stream>>>(
            q0, cp,
            p_hist + (size_t)s * slab, q_hist + (size_t)s * slab,
            p_hist + (size_t)(s + 1) * slab, q_hist + (size_t)(s + 1) * slab,
            W1, b1, W2, b2, W3, b3, wt, 0);
    }

    flow_step0<<<NTPL / 4, 256, 0, stream>>>(tpl, cp, q0, out, wt);
    flow_rest<<<BTS * NTPL / 16, 256, 0, stream>>>(p_hist, q_hist, out, wt);
}